// Round 1
// baseline (955.478 us; speedup 1.0000x reference)
//
#include <hip/hip_runtime.h>
#include <math.h>

#define FEAT  128
#define NE    128
#define INTER 512
#define EMB   512
#define TB    16

static constexpr float F_EPS    = 1e-6f;
static constexpr float F_LN_EPS = 1e-5f;

// One-time transpose: w1 [512][128] -> w1T [128][512], w2 [512][512] -> w2T [512][512]
__global__ void vc_transpose(const float* __restrict__ w1,
                             const float* __restrict__ w2,
                             float* __restrict__ w1T,
                             float* __restrict__ w2T) {
    int tid = blockIdx.x * blockDim.x + threadIdx.x;
    if (tid < INTER * FEAT) {
        int i = tid >> 7, f = tid & 127;
        w1T[f * INTER + i] = w1[tid];
    }
    if (tid < EMB * INTER) {
        int e = tid >> 9, i = tid & 511;
        w2T[i * EMB + e] = w2[tid];
    }
}

__device__ __forceinline__ float gelu_exact(float v) {
    return 0.5f * v * (1.0f + erff(v * 0.70710678118654752440f));
}

__global__ __launch_bounds__(256) void vc_main(
    const float* __restrict__ x,   const float* __restrict__ gu,
    const float* __restrict__ lnw, const float* __restrict__ lnb,
    const float* __restrict__ w1T, const float* __restrict__ b1,
    const float* __restrict__ w2T, const float* __restrict__ b2,
    const float* __restrict__ emb, const float* __restrict__ scl,
    float* __restrict__ out)
{
    __shared__ __align__(16) float s_xn[TB][FEAT + 4];
    __shared__ __align__(16) float s_h [TB][INTER + 4];
    __shared__ int   s_code[TB][NE];
    __shared__ float s_pre[TB];

    const int  tid  = threadIdx.x;
    const long tok0 = (long)blockIdx.x * TB;

    // ---------------- phase 0: scale, unit-norm, LayerNorm ----------------
    {
        const int t  = tid >> 4;        // 0..15 token in tile
        const int fq = tid & 15;        // 16 lanes per token
        const int f0 = fq * 8;
        const float* xr = x + (tok0 + t) * FEAT + f0;
        float v[8];
        #pragma unroll
        for (int k = 0; k < 8; ++k) v[k] = xr[k] / (scl[f0 + k] + F_EPS);

        float ss = 0.f;
        #pragma unroll
        for (int k = 0; k < 8; ++k) ss += v[k] * v[k];
        #pragma unroll
        for (int o = 1; o < 16; o <<= 1) ss += __shfl_xor(ss, o, 64);
        const float pre = sqrtf(ss);
        if (fq == 0) s_pre[t] = pre;

        const float ip = 1.0f / (pre + F_EPS);
        #pragma unroll
        for (int k = 0; k < 8; ++k) v[k] *= ip;

        float sm = 0.f;
        #pragma unroll
        for (int k = 0; k < 8; ++k) sm += v[k];
        #pragma unroll
        for (int o = 1; o < 16; o <<= 1) sm += __shfl_xor(sm, o, 64);
        const float mu = sm * (1.0f / 128.0f);

        float vv = 0.f;
        #pragma unroll
        for (int k = 0; k < 8; ++k) { float d = v[k] - mu; vv += d * d; }
        #pragma unroll
        for (int o = 1; o < 16; o <<= 1) vv += __shfl_xor(vv, o, 64);
        const float rst = 1.0f / sqrtf(vv * (1.0f / 128.0f) + F_LN_EPS);

        #pragma unroll
        for (int k = 0; k < 8; ++k)
            s_xn[t][f0 + k] = (v[k] - mu) * rst * lnw[f0 + k] + lnb[f0 + k];
    }
    __syncthreads();

    // ---------------- phase 1: h = gelu(xn @ w1^T + b1) ----------------
    {
        const int iq = tid & 127;       // i-quad index
        const int th = tid >> 7;        // token half: 0 or 1
        const int i0 = iq * 4;
        float acc[4][8];
        #pragma unroll
        for (int j = 0; j < 4; ++j)
            #pragma unroll
            for (int t = 0; t < 8; ++t) acc[j][t] = 0.f;

        const float* wp = w1T + i0;
        for (int f4 = 0; f4 < FEAT / 4; ++f4) {
            const float4 wa = *(const float4*)(wp + (size_t)(f4 * 4 + 0) * INTER);
            const float4 wb = *(const float4*)(wp + (size_t)(f4 * 4 + 1) * INTER);
            const float4 wc = *(const float4*)(wp + (size_t)(f4 * 4 + 2) * INTER);
            const float4 wd = *(const float4*)(wp + (size_t)(f4 * 4 + 3) * INTER);
            #pragma unroll
            for (int t = 0; t < 8; ++t) {
                const float4 xv = *(const float4*)&s_xn[th * 8 + t][f4 * 4];
                acc[0][t] += xv.x * wa.x + xv.y * wb.x + xv.z * wc.x + xv.w * wd.x;
                acc[1][t] += xv.x * wa.y + xv.y * wb.y + xv.z * wc.y + xv.w * wd.y;
                acc[2][t] += xv.x * wa.z + xv.y * wb.z + xv.z * wc.z + xv.w * wd.z;
                acc[3][t] += xv.x * wa.w + xv.y * wb.w + xv.z * wc.w + xv.w * wd.w;
            }
        }
        const float bj0 = b1[i0], bj1 = b1[i0 + 1], bj2 = b1[i0 + 2], bj3 = b1[i0 + 3];
        #pragma unroll
        for (int t = 0; t < 8; ++t) {
            float4 hv;
            hv.x = gelu_exact(acc[0][t] + bj0);
            hv.y = gelu_exact(acc[1][t] + bj1);
            hv.z = gelu_exact(acc[2][t] + bj2);
            hv.w = gelu_exact(acc[3][t] + bj3);
            *(float4*)&s_h[th * 8 + t][i0] = hv;
        }
    }
    __syncthreads();

    // ---------------- phase 2: logits = h @ w2^T + b2; gumbel argmax ----------------
    {
        const int g  = tid & 127;       // group index 0..127
        const int th = tid >> 7;
        const int e0 = g * 4;
        float acc[4][8];
        #pragma unroll
        for (int j = 0; j < 4; ++j)
            #pragma unroll
            for (int t = 0; t < 8; ++t) acc[j][t] = 0.f;

        const float* wp = w2T + e0;
        for (int i4 = 0; i4 < INTER / 4; ++i4) {
            const float4 wa = *(const float4*)(wp + (size_t)(i4 * 4 + 0) * EMB);
            const float4 wb = *(const float4*)(wp + (size_t)(i4 * 4 + 1) * EMB);
            const float4 wc = *(const float4*)(wp + (size_t)(i4 * 4 + 2) * EMB);
            const float4 wd = *(const float4*)(wp + (size_t)(i4 * 4 + 3) * EMB);
            #pragma unroll
            for (int t = 0; t < 8; ++t) {
                const float4 hv = *(const float4*)&s_h[th * 8 + t][i4 * 4];
                acc[0][t] += hv.x * wa.x + hv.y * wb.x + hv.z * wc.x + hv.w * wd.x;
                acc[1][t] += hv.x * wa.y + hv.y * wb.y + hv.z * wc.y + hv.w * wd.y;
                acc[2][t] += hv.x * wa.z + hv.y * wb.z + hv.z * wc.z + hv.w * wd.z;
                acc[3][t] += hv.x * wa.w + hv.y * wb.w + hv.z * wc.w + hv.w * wd.w;
            }
        }
        const float be0 = b2[e0], be1 = b2[e0 + 1], be2 = b2[e0 + 2], be3 = b2[e0 + 3];
        #pragma unroll
        for (int t = 0; t < 8; ++t) {
            const long token = tok0 + th * 8 + t;
            const float4 u = *(const float4*)(gu + token * (long)(NE * 4) + e0);
            const float l0 = acc[0][t] + be0 - logf(-logf(u.x));
            const float l1 = acc[1][t] + be1 - logf(-logf(u.y));
            const float l2 = acc[2][t] + be2 - logf(-logf(u.z));
            const float l3 = acc[3][t] + be3 - logf(-logf(u.w));
            int c = 0; float best = l0;                 // np.argmax: first max wins
            if (l1 > best) { best = l1; c = 1; }
            if (l2 > best) { best = l2; c = 2; }
            if (l3 > best) { best = l3; c = 3; }
            s_code[th * 8 + t][g] = c;
        }
    }
    __syncthreads();

    // ---------------- phase 3: decode, renormalize, write ----------------
    {
        const int t  = tid >> 4;
        const int fq = tid & 15;
        const int f0 = fq * 8;
        float r[8];
        #pragma unroll
        for (int k = 0; k < 8; ++k) r[k] = 0.f;

        const float* ebase = emb + f0;
        for (int gg = 0; gg < NE; ++gg) {
            const int c = s_code[t][gg];
            const float wb0 = (c == 0 || c == 2) ? 1.0f : 0.0f;
            const float wb1 = (c == 1 || c == 2) ? 1.0f : 0.0f;
            const float4* r0 = (const float4*)(ebase + (size_t)(2 * gg) * FEAT);
            const float4* r1 = (const float4*)(ebase + (size_t)(2 * gg + 1) * FEAT);
            const float4 a0 = r0[0], a1 = r0[1];
            const float4 c0 = r1[0], c1 = r1[1];
            r[0] += wb0 * a0.x; r[1] += wb0 * a0.y; r[2] += wb0 * a0.z; r[3] += wb0 * a0.w;
            r[4] += wb0 * a1.x; r[5] += wb0 * a1.y; r[6] += wb0 * a1.z; r[7] += wb0 * a1.w;
            r[0] += wb1 * c0.x; r[1] += wb1 * c0.y; r[2] += wb1 * c0.z; r[3] += wb1 * c0.w;
            r[4] += wb1 * c1.x; r[5] += wb1 * c1.y; r[6] += wb1 * c1.z; r[7] += wb1 * c1.w;
        }
        float ss = 0.f;
        #pragma unroll
        for (int k = 0; k < 8; ++k) ss += r[k] * r[k];
        #pragma unroll
        for (int o = 1; o < 16; o <<= 1) ss += __shfl_xor(ss, o, 64);
        const float post  = sqrtf(ss);
        const float ipost = 1.0f / (post + F_EPS);
        const float pm    = s_pre[t] + F_EPS;
        float* orow = out + (tok0 + t) * FEAT + f0;
        #pragma unroll
        for (int k = 0; k < 8; ++k) {
            float o = r[k] * ipost;
            o = o * pm;
            o = o * (scl[f0 + k] + F_EPS);
            orow[k] = o;
        }
    }
}

extern "C" void kernel_launch(void* const* d_in, const int* in_sizes, int n_in,
                              void* d_out, int out_size, void* d_ws, size_t ws_size,
                              hipStream_t stream) {
    const float* x   = (const float*)d_in[0];
    const float* gu  = (const float*)d_in[1];
    const float* lnw = (const float*)d_in[2];
    const float* lnb = (const float*)d_in[3];
    const float* w1  = (const float*)d_in[4];
    const float* b1  = (const float*)d_in[5];
    const float* w2  = (const float*)d_in[6];
    const float* b2  = (const float*)d_in[7];
    const float* emb = (const float*)d_in[8];
    const float* scl = (const float*)d_in[9];
    float* out = (float*)d_out;

    float* w1T = (float*)d_ws;                 // 128*512 floats = 256 KB
    float* w2T = w1T + INTER * FEAT;           // 512*512 floats = 1 MB

    hipLaunchKernelGGL(vc_transpose, dim3((EMB * INTER) / 256), dim3(256), 0, stream,
                       w1, w2, w1T, w2T);

    const int ntok = in_sizes[0] / FEAT;       // 65536
    hipLaunchKernelGGL(vc_main, dim3(ntok / TB), dim3(256), 0, stream,
                       x, gu, lnw, lnb, w1T, b1, w2T, b2, emb, scl, out);
}

// Round 3
// 548.310 us; speedup vs baseline: 1.7426x; 1.7426x over previous
//
#include <hip/hip_runtime.h>
#include <math.h>

#define FEAT  128
#define INTER 512
#define EMB   512
#define TB    64

typedef short s16x8 __attribute__((ext_vector_type(8)));
typedef float f32x4 __attribute__((ext_vector_type(4)));

static constexpr float F_EPS    = 1e-6f;
static constexpr float F_LN_EPS = 1e-5f;

#define MFMA(a,b,c) __builtin_amdgcn_mfma_f32_16x16x32_bf16(a,b,c,0,0,0)

// u16-element offsets inside wsP (total 2 MB)
#define W1BASE 0                 // 128 frags * 1536 u16 (hi|mid|lo, 512 each)
#define W2BASE 196608            // 512 frags * 1536 u16
#define EBASE  983040            // 64  frags * 1024 u16 (hi|lo)

__device__ __forceinline__ unsigned short f2bf(float f) {
    union { float f; unsigned u; } v; v.f = f;
    unsigned r = v.u + 0x7FFFu + ((v.u >> 16) & 1u);
    return (unsigned short)(r >> 16);
}
__device__ __forceinline__ float bf2f(unsigned short h) {
    union { unsigned u; float f; } v; v.u = ((unsigned)h) << 16;
    return v.f;
}
__device__ __forceinline__ void split3(float x, unsigned short& h,
                                       unsigned short& m, unsigned short& l) {
    h = f2bf(x);
    float r1 = x - bf2f(h);
    m = f2bf(r1);
    l = f2bf(r1 - bf2f(m));
}
__device__ __forceinline__ float gelu_exact(float v) {
    return 0.5f * v * (1.0f + erff(v * 0.70710678118654752440f));
}

// Pack w1/w2 into 3-split, emb into 2-split MFMA B-fragments.
// Frag lane l holds B[k = kt*32 + 8*(l>>4) + i][n = nt*16 + (l&15)], i=0..7.
__global__ __launch_bounds__(256) void vc_pack(const float* __restrict__ w1,
                                               const float* __restrict__ w2,
                                               const float* __restrict__ emb,
                                               unsigned short* __restrict__ P) {
    int id = blockIdx.x * 256 + threadIdx.x;
    int fid = id >> 6, l = id & 63;
    if (fid >= 704) return;
    int lr = l & 15, lq = l >> 4;
    float v[8];
    size_t dst;
    int three = 1;
    if (fid < 128) {
        int kt = fid >> 5, nt = fid & 31;
        const float* s = w1 + (size_t)(nt * 16 + lr) * FEAT + kt * 32 + 8 * lq;
        #pragma unroll
        for (int i = 0; i < 8; ++i) v[i] = s[i];
        dst = W1BASE + (size_t)fid * 1536;
    } else if (fid < 640) {
        int f2 = fid - 128, kt = f2 >> 5, nt = f2 & 31;
        const float* s = w2 + (size_t)(nt * 16 + lr) * INTER + kt * 32 + 8 * lq;
        #pragma unroll
        for (int i = 0; i < 8; ++i) v[i] = s[i];
        dst = W2BASE + (size_t)f2 * 1536;
    } else {
        int f3 = fid - 640, kt = f3 >> 3, nt = f3 & 7;
        #pragma unroll
        for (int i = 0; i < 8; ++i)
            v[i] = emb[(size_t)(kt * 32 + 8 * lq + i) * FEAT + nt * 16 + lr];
        dst = EBASE + (size_t)f3 * 1024;
        three = 0;
    }
    s16x8 vh, vm, vl;
    #pragma unroll
    for (int i = 0; i < 8; ++i) {
        unsigned short a, b, c;
        split3(v[i], a, b, c);
        vh[i] = (short)a; vm[i] = (short)b; vl[i] = (short)c;
    }
    *(s16x8*)(P + dst + l * 8)       = vh;
    *(s16x8*)(P + dst + 512 + l * 8) = vm;   // for emb this is the lo plane
    if (three) *(s16x8*)(P + dst + 1024 + l * 8) = vl;
}

__global__ __launch_bounds__(512, 2) void vc_fused(
    const float* __restrict__ x,   const float* __restrict__ gu,
    const float* __restrict__ lnw, const float* __restrict__ lnb,
    const float* __restrict__ b1,  const float* __restrict__ b2,
    const float* __restrict__ scl, const unsigned short* __restrict__ wsP,
    float* __restrict__ out)
{
    // LDS map, 158208 B total (<= 163840), 1 block/CU:
    //  [0,      49152)  xn 3 planes of [4mt][4kt][64lane][8] u16 (8192 u16 each)
    //  [49152, 147456)  h  3 planes of [64][256] u16, 16B-granule XOR swizzle
    //  [147456,155648)  sC [64][32] u32 (code bytes, col-swizzled)
    //  [155648,158208)  sPre[64] | sPart[8][64] | sFac[64]
    __shared__ __align__(16) unsigned char smem[158208];
    unsigned short* sXn = (unsigned short*)smem;
    unsigned short* sH  = (unsigned short*)(smem + 49152);
    unsigned*       sC  = (unsigned*)(smem + 147456);
    float*          sPre  = (float*)(smem + 155648);
    float*          sPart = (float*)(smem + 155904);
    float*          sFac  = (float*)(smem + 157952);

    const int tid = threadIdx.x;
    const int w  = tid >> 6;
    const int l  = tid & 63;
    const int lr = l & 15, lq = l >> 4;
    const long tok0 = (long)blockIdx.x * TB;

    // ---------------- phase 0: scale, unit-norm, LayerNorm, 3-split frags ----
    {
        const int t = tid >> 3;            // token 0..63
        const int q = tid & 7;             // 16-feat chunk
        const float* xr = x + (tok0 + t) * FEAT + q * 16;
        float v[16];
        #pragma unroll
        for (int k = 0; k < 16; ++k) v[k] = xr[k] / (scl[q * 16 + k] + F_EPS);
        float ss = 0.f;
        #pragma unroll
        for (int k = 0; k < 16; ++k) ss += v[k] * v[k];
        ss += __shfl_xor(ss, 1); ss += __shfl_xor(ss, 2); ss += __shfl_xor(ss, 4);
        const float pre = sqrtf(ss);
        if (q == 0) sPre[t] = pre;
        const float ip = 1.0f / (pre + F_EPS);
        #pragma unroll
        for (int k = 0; k < 16; ++k) v[k] *= ip;
        float sm = 0.f;
        #pragma unroll
        for (int k = 0; k < 16; ++k) sm += v[k];
        sm += __shfl_xor(sm, 1); sm += __shfl_xor(sm, 2); sm += __shfl_xor(sm, 4);
        const float mu = sm * (1.0f / 128.0f);
        float vv = 0.f;
        #pragma unroll
        for (int k = 0; k < 16; ++k) { float d = v[k] - mu; vv += d * d; }
        vv += __shfl_xor(vv, 1); vv += __shfl_xor(vv, 2); vv += __shfl_xor(vv, 4);
        const float rst = 1.0f / sqrtf(vv * (1.0f / 128.0f) + F_LN_EPS);

        const int mt = t >> 4;
        #pragma unroll
        for (int jh = 0; jh < 2; ++jh) {
            const int fb  = 2 * q + jh;
            const int kt  = fb >> 2;
            const int sub = fb & 3;
            const size_t base = ((size_t)(mt * 4 + kt) * 64 + (t & 15) + 16 * sub) * 8;
            s16x8 vh, vm, vlo;
            #pragma unroll
            for (int i = 0; i < 8; ++i) {
                const int k = jh * 8 + i;
                const float xnv = (v[k] - mu) * rst * lnw[q * 16 + k] + lnb[q * 16 + k];
                unsigned short a, b, c;
                split3(xnv, a, b, c);
                vh[i] = (short)a; vm[i] = (short)b; vlo[i] = (short)c;
            }
            *(s16x8*)(sXn + base)         = vh;
            *(s16x8*)(sXn + 8192 + base)  = vm;
            *(s16x8*)(sXn + 16384 + base) = vlo;
        }
    }
    __syncthreads();

    f32x4 acc2[4][4];
    #pragma unroll
    for (int m = 0; m < 4; ++m)
        #pragma unroll
        for (int n = 0; n < 4; ++n)
            #pragma unroll
            for (int r = 0; r < 4; ++r) acc2[m][n][r] = 0.f;

    for (int half = 0; half < 2; ++half) {
        // -------- GEMM1 over n-half: 16 n-tiles, 6-term split-bf16 --------
        f32x4 acc1[4][2];
        #pragma unroll
        for (int m = 0; m < 4; ++m)
            #pragma unroll
            for (int n = 0; n < 2; ++n)
                #pragma unroll
                for (int r = 0; r < 4; ++r) acc1[m][n][r] = 0.f;

        #pragma unroll
        for (int kt = 0; kt < 4; ++kt) {
            s16x8 A[4][3];
            #pragma unroll
            for (int m = 0; m < 4; ++m) {
                const size_t base = ((size_t)(m * 4 + kt) * 64 + l) * 8;
                A[m][0] = *(const s16x8*)(sXn + base);
                A[m][1] = *(const s16x8*)(sXn + 8192 + base);
                A[m][2] = *(const s16x8*)(sXn + 16384 + base);
            }
            #pragma unroll
            for (int ntl = 0; ntl < 2; ++ntl) {
                const int nt = half * 16 + w * 2 + ntl;
                const unsigned short* bp = wsP + W1BASE + (size_t)(kt * 32 + nt) * 1536 + l * 8;
                const s16x8 bh = *(const s16x8*)bp;
                const s16x8 bm = *(const s16x8*)(bp + 512);
                const s16x8 bl = *(const s16x8*)(bp + 1024);
                #pragma unroll
                for (int m = 0; m < 4; ++m) {
                    f32x4 c = acc1[m][ntl];
                    c = MFMA(A[m][1], bm, c);    // mid*mid   (~2^-18)
                    c = MFMA(A[m][2], bh, c);    // lo*hi     (~2^-18)
                    c = MFMA(A[m][0], bl, c);    // hi*lo     (~2^-18)
                    c = MFMA(A[m][1], bh, c);    // mid*hi    (~2^-9)
                    c = MFMA(A[m][0], bm, c);    // hi*mid    (~2^-9)
                    c = MFMA(A[m][0], bh, c);    // hi*hi
                    acc1[m][ntl] = c;
                }
            }
        }

        // -------- bias + gelu, 3-split, write h planes --------
        {
            float b1v[2];
            #pragma unroll
            for (int ntl = 0; ntl < 2; ++ntl)
                b1v[ntl] = b1[half * 256 + (w * 2 + ntl) * 16 + lr];
            #pragma unroll
            for (int m = 0; m < 4; ++m)
                #pragma unroll
                for (int ntl = 0; ntl < 2; ++ntl)
                    #pragma unroll
                    for (int r = 0; r < 4; ++r) {
                        const float h = gelu_exact(acc1[m][ntl][r] + b1v[ntl]);
                        unsigned short hh, hm, hl;
                        split3(h, hh, hm, hl);
                        const int tokr = 4 * lq + r;
                        const int row  = m * 16 + tokr;
                        const int nl   = (w * 2 + ntl) * 16 + lr;      // 0..255
                        const int gsw  = (nl >> 3) ^ (tokr & 7);
                        const size_t off = (size_t)row * 256 + gsw * 8 + (nl & 7);
                        sH[off]          = hh;
                        sH[16384 + off]  = hm;
                        sH[32768 + off]  = hl;
                    }
        }
        __syncthreads();

        // -------- GEMM2 partial over k-half: 8 k-tiles, 6-term --------
        for (int kk = 0; kk < 8; ++kk) {
            s16x8 A[4][3];
            #pragma unroll
            for (int m = 0; m < 4; ++m) {
                const int row = m * 16 + lr;
                const int gsw = (kk * 4 + lq) ^ (lr & 7);
                const size_t off = (size_t)row * 256 + (size_t)gsw * 8;
                A[m][0] = *(const s16x8*)(sH + off);
                A[m][1] = *(const s16x8*)(sH + 16384 + off);
                A[m][2] = *(const s16x8*)(sH + 32768 + off);
            }
            #pragma unroll
            for (int ntl = 0; ntl < 4; ++ntl) {
                const int fid2 = (half * 8 + kk) * 32 + (w * 4 + ntl);
                const unsigned short* bp = wsP + W2BASE + (size_t)fid2 * 1536 + l * 8;
                const s16x8 bh = *(const s16x8*)bp;
                const s16x8 bm = *(const s16x8*)(bp + 512);
                const s16x8 bl = *(const s16x8*)(bp + 1024);
                #pragma unroll
                for (int m = 0; m < 4; ++m) {
                    f32x4 c = acc2[m][ntl];
                    c = MFMA(A[m][1], bm, c);
                    c = MFMA(A[m][2], bh, c);
                    c = MFMA(A[m][0], bl, c);
                    c = MFMA(A[m][1], bh, c);
                    c = MFMA(A[m][0], bm, c);
                    c = MFMA(A[m][0], bh, c);
                    acc2[m][ntl] = c;
                }
            }
        }
        __syncthreads();
    }

    // ---------------- phase 4: bias + gumbel + quad argmax -> sC --------------
    {
        float b2v[4];
        #pragma unroll
        for (int ntl = 0; ntl < 4; ++ntl) b2v[ntl] = b2[w * 64 + ntl * 16 + lr];
        const int qq  = lr >> 2;
        const int cls = l & 3;
        #pragma unroll
        for (int m = 0; m < 4; ++m)
            #pragma unroll
            for (int ntl = 0; ntl < 4; ++ntl) {
                #pragma unroll
                for (int r = 0; r < 4; ++r) {
                    const long tg = tok0 + m * 16 + 4 * lq + r;
                    const float u = gu[tg * 512 + w * 64 + ntl * 16 + lr];
                    float v = acc2[m][ntl][r] + b2v[ntl] - logf(-logf(u));
                    int   ci = cls;
                    float v1 = __shfl_xor(v, 1); int c1 = __shfl_xor(ci, 1);
                    if (v1 > v || (v1 == v && c1 < ci)) { v = v1; ci = c1; }
                    float v2 = __shfl_xor(v, 2); int c2 = __shfl_xor(ci, 2);
                    if (v2 > v || (v2 == v && c2 < ci)) { v = v2; ci = c2; }
                    if (cls == 0) {
                        const int row = m * 16 + 4 * lq + r;
                        const int col = (w * 4 + ntl) ^ ((row & 7) << 2);
                        ((unsigned char*)(sC + row * 32 + col))[qq] = (unsigned char)ci;
                    }
                }
            }
    }
    __syncthreads();

    // ---------------- phase 5: decode (2-term MFMA, codes exact) --------------
    f32x4 accd[4];
    #pragma unroll
    for (int m = 0; m < 4; ++m)
        #pragma unroll
        for (int r = 0; r < 4; ++r) accd[m][r] = 0.f;

    #pragma unroll
    for (int kt = 0; kt < 8; ++kt) {
        const unsigned short* bp = wsP + EBASE + (size_t)(kt * 8 + w) * 1024 + l * 8;
        const s16x8 bh = *(const s16x8*)bp;
        const s16x8 bl = *(const s16x8*)(bp + 512);
        #pragma unroll
        for (int m = 0; m < 4; ++m) {
            const int row = m * 16 + lr;
            const int col = (kt * 4 + lq) ^ ((row & 7) << 2);
            const unsigned cw = sC[row * 32 + col];
            s16x8 a;
            #pragma unroll
            for (int q2 = 0; q2 < 4; ++q2) {
                const unsigned c = (cw >> (8 * q2)) & 0xffu;
                a[2 * q2]     = ((c & 1u) == 0u) ? (short)0x3F80 : (short)0;
                a[2 * q2 + 1] = (((c + 1u) & 2u) != 0u) ? (short)0x3F80 : (short)0;
            }
            accd[m] = MFMA(a, bh, accd[m]);
            accd[m] = MFMA(a, bl, accd[m]);
        }
    }
    __syncthreads();

    // ---------------- phase 6: postscale norm + output ------------------------
    {
        #pragma unroll
        for (int m = 0; m < 4; ++m) {
            float ps[4];
            #pragma unroll
            for (int r = 0; r < 4; ++r) {
                float s = accd[m][r] * accd[m][r];
                s += __shfl_xor(s, 1); s += __shfl_xor(s, 2);
                s += __shfl_xor(s, 4); s += __shfl_xor(s, 8);
                ps[r] = s;
            }
            if (lr == 0)
                *(float4*)(sPart + w * 64 + m * 16 + 4 * lq) =
                    make_float4(ps[0], ps[1], ps[2], ps[3]);
        }
    }
    __syncthreads();
    if (tid < 64) {
        float ssum = 0.f;
        #pragma unroll
        for (int ww = 0; ww < 8; ++ww) ssum += sPart[ww * 64 + tid];
        const float post = sqrtf(ssum);
        sFac[tid] = (1.0f / (post + F_EPS)) * (sPre[tid] + F_EPS);
    }
    __syncthreads();
    {
        const float sclv = scl[w * 16 + lr] + F_EPS;
        #pragma unroll
        for (int m = 0; m < 4; ++m)
            #pragma unroll
            for (int r = 0; r < 4; ++r) {
                const int tokr = m * 16 + 4 * lq + r;
                const float o = accd[m][r] * sFac[tokr] * sclv;
                out[(tok0 + tokr) * FEAT + w * 16 + lr] = o;
            }
    }
}

extern "C" void kernel_launch(void* const* d_in, const int* in_sizes, int n_in,
                              void* d_out, int out_size, void* d_ws, size_t ws_size,
                              hipStream_t stream) {
    const float* x   = (const float*)d_in[0];
    const float* gu  = (const float*)d_in[1];
    const float* lnw = (const float*)d_in[2];
    const float* lnb = (const float*)d_in[3];
    const float* w1  = (const float*)d_in[4];
    const float* b1  = (const float*)d_in[5];
    const float* w2  = (const float*)d_in[6];
    const float* b2  = (const float*)d_in[7];
    const float* emb = (const float*)d_in[8];
    const float* scl = (const float*)d_in[9];
    float* out = (float*)d_out;

    unsigned short* wsP = (unsigned short*)d_ws;   // needs 2 MB

    hipLaunchKernelGGL(vc_pack, dim3(176), dim3(256), 0, stream, w1, w2, emb, wsP);

    const int ntok = in_sizes[0] / FEAT;           // 65536
    hipLaunchKernelGGL(vc_fused, dim3(ntok / TB), dim3(512), 0, stream,
                       x, gu, lnw, lnb, b1, b2, scl, wsP, out);
}

// Round 4
// 373.160 us; speedup vs baseline: 2.5605x; 1.4694x over previous
//
#include <hip/hip_runtime.h>
#include <math.h>

#define FEAT  128
#define INTER 512
#define EMB   512
#define TB    64

typedef short s16x8 __attribute__((ext_vector_type(8)));
typedef float f32x4 __attribute__((ext_vector_type(4)));

static constexpr float F_EPS    = 1e-6f;
static constexpr float F_LN_EPS = 1e-5f;

#define MFMA(a,b,c) __builtin_amdgcn_mfma_f32_16x16x32_bf16(a,b,c,0,0,0)

// u16-element offsets inside wsP (total 2 MB)
#define W1BASE 0                 // 128 frags * 1536 u16 (hi|mid|lo, 512 each)
#define W2BASE 196608            // 512 frags * 1536 u16
#define EBASE  983040            // 64  frags * 1024 u16 (hi|lo)

__device__ __forceinline__ unsigned short f2bf(float f) {
    union { float f; unsigned u; } v; v.f = f;
    unsigned r = v.u + 0x7FFFu + ((v.u >> 16) & 1u);
    return (unsigned short)(r >> 16);
}
__device__ __forceinline__ float bf2f(unsigned short h) {
    union { unsigned u; float f; } v; v.u = ((unsigned)h) << 16;
    return v.f;
}
__device__ __forceinline__ void split3(float x, unsigned short& h,
                                       unsigned short& m, unsigned short& l) {
    h = f2bf(x);
    float r1 = x - bf2f(h);
    m = f2bf(r1);
    l = f2bf(r1 - bf2f(m));
}
__device__ __forceinline__ float gelu_exact(float v) {
    return 0.5f * v * (1.0f + erff(v * 0.70710678118654752440f));
}

// Pack w1/w2 into 3-split, emb into 2-split MFMA B-fragments.
// Frag lane l holds B[k = kt*32 + 8*(l>>4) + i][n = nt*16 + (l&15)], i=0..7.
__global__ __launch_bounds__(256) void vc_pack(const float* __restrict__ w1,
                                               const float* __restrict__ w2,
                                               const float* __restrict__ emb,
                                               unsigned short* __restrict__ P) {
    int id = blockIdx.x * 256 + threadIdx.x;
    int fid = id >> 6, l = id & 63;
    if (fid >= 704) return;
    int lr = l & 15, lq = l >> 4;
    float v[8];
    size_t dst;
    int three = 1;
    if (fid < 128) {
        int kt = fid >> 5, nt = fid & 31;
        const float* s = w1 + (size_t)(nt * 16 + lr) * FEAT + kt * 32 + 8 * lq;
        #pragma unroll
        for (int i = 0; i < 8; ++i) v[i] = s[i];
        dst = W1BASE + (size_t)fid * 1536;
    } else if (fid < 640) {
        int f2 = fid - 128, kt = f2 >> 5, nt = f2 & 31;
        const float* s = w2 + (size_t)(nt * 16 + lr) * INTER + kt * 32 + 8 * lq;
        #pragma unroll
        for (int i = 0; i < 8; ++i) v[i] = s[i];
        dst = W2BASE + (size_t)f2 * 1536;
    } else {
        int f3 = fid - 640, kt = f3 >> 3, nt = f3 & 7;
        #pragma unroll
        for (int i = 0; i < 8; ++i)
            v[i] = emb[(size_t)(kt * 32 + 8 * lq + i) * FEAT + nt * 16 + lr];
        dst = EBASE + (size_t)f3 * 1024;
        three = 0;
    }
    s16x8 vh, vm, vl;
    #pragma unroll
    for (int i = 0; i < 8; ++i) {
        unsigned short a, b, c;
        split3(v[i], a, b, c);
        vh[i] = (short)a; vm[i] = (short)b; vl[i] = (short)c;
    }
    *(s16x8*)(P + dst + l * 8)       = vh;
    *(s16x8*)(P + dst + 512 + l * 8) = vm;   // for emb this is the lo plane
    if (three) *(s16x8*)(P + dst + 1024 + l * 8) = vl;
}

__global__ __launch_bounds__(1024) void vc_fused(
    const float* __restrict__ x,   const float* __restrict__ gu,
    const float* __restrict__ lnw, const float* __restrict__ lnb,
    const float* __restrict__ b1,  const float* __restrict__ b2,
    const float* __restrict__ scl, const unsigned short* __restrict__ wsP,
    float* __restrict__ out)
{
    // LDS map, 158208 B total, 16 waves/block -> 4 waves/SIMD:
    //  [0,      49152)  xn 3 planes of [4mt][4kt][64lane][8] u16
    //  [49152, 147456)  h  3 planes of [64][256] u16, 16B-granule XOR swizzle
    //  [147456,155648)  sC [64][32] u32 (code bytes, col-swizzled)
    //  [155648,158208)  sPre[64] | sPart[8][64] | sFac[64]
    __shared__ __align__(16) unsigned char smem[158208];
    unsigned short* sXn = (unsigned short*)smem;
    unsigned short* sH  = (unsigned short*)(smem + 49152);
    unsigned*       sC  = (unsigned*)(smem + 147456);
    float*          sPre  = (float*)(smem + 155648);
    float*          sPart = (float*)(smem + 155904);
    float*          sFac  = (float*)(smem + 157952);

    const int tid = threadIdx.x;
    const int w  = tid >> 6;           // wave 0..15
    const int l  = tid & 63;
    const int lr = l & 15, lq = l >> 4;
    const long tok0 = (long)blockIdx.x * TB;

    // ---------------- phase 0: scale, unit-norm, LayerNorm, 3-split frags ----
    {
        const int t = tid >> 4;            // token 0..63
        const int q = tid & 15;            // feat octet 0..15
        const float* xr = x + (tok0 + t) * FEAT + q * 8;
        float v[8];
        #pragma unroll
        for (int k = 0; k < 8; ++k) v[k] = xr[k] / (scl[q * 8 + k] + F_EPS);
        float ss = 0.f;
        #pragma unroll
        for (int k = 0; k < 8; ++k) ss += v[k] * v[k];
        ss += __shfl_xor(ss, 1); ss += __shfl_xor(ss, 2);
        ss += __shfl_xor(ss, 4); ss += __shfl_xor(ss, 8);
        const float pre = sqrtf(ss);
        if (q == 0) sPre[t] = pre;
        const float ip = 1.0f / (pre + F_EPS);
        #pragma unroll
        for (int k = 0; k < 8; ++k) v[k] *= ip;
        float sm = 0.f;
        #pragma unroll
        for (int k = 0; k < 8; ++k) sm += v[k];
        sm += __shfl_xor(sm, 1); sm += __shfl_xor(sm, 2);
        sm += __shfl_xor(sm, 4); sm += __shfl_xor(sm, 8);
        const float mu = sm * (1.0f / 128.0f);
        float vv = 0.f;
        #pragma unroll
        for (int k = 0; k < 8; ++k) { float d = v[k] - mu; vv += d * d; }
        vv += __shfl_xor(vv, 1); vv += __shfl_xor(vv, 2);
        vv += __shfl_xor(vv, 4); vv += __shfl_xor(vv, 8);
        const float rst = 1.0f / sqrtf(vv * (1.0f / 128.0f) + F_LN_EPS);

        const int mt  = t >> 4;
        const int kt  = q >> 2;
        const int sub = q & 3;
        const size_t base = ((size_t)(mt * 4 + kt) * 64 + (t & 15) + 16 * sub) * 8;
        s16x8 vh, vm, vlo;
        #pragma unroll
        for (int i = 0; i < 8; ++i) {
            const float xnv = (v[i] - mu) * rst * lnw[q * 8 + i] + lnb[q * 8 + i];
            unsigned short a, b, c;
            split3(xnv, a, b, c);
            vh[i] = (short)a; vm[i] = (short)b; vlo[i] = (short)c;
        }
        *(s16x8*)(sXn + base)         = vh;
        *(s16x8*)(sXn + 8192 + base)  = vm;
        *(s16x8*)(sXn + 16384 + base) = vlo;
    }
    __syncthreads();

    f32x4 acc2[4][2];
    #pragma unroll
    for (int m = 0; m < 4; ++m)
        #pragma unroll
        for (int n = 0; n < 2; ++n)
            #pragma unroll
            for (int r = 0; r < 4; ++r) acc2[m][n][r] = 0.f;

    for (int half = 0; half < 2; ++half) {
        // -------- GEMM1 over n-half: 1 n-tile/wave, 6-term split-bf16 --------
        f32x4 acc1[4];
        #pragma unroll
        for (int m = 0; m < 4; ++m)
            #pragma unroll
            for (int r = 0; r < 4; ++r) acc1[m][r] = 0.f;

        #pragma unroll
        for (int kt = 0; kt < 4; ++kt) {
            s16x8 A[4][3];
            #pragma unroll
            for (int m = 0; m < 4; ++m) {
                const size_t base = ((size_t)(m * 4 + kt) * 64 + l) * 8;
                A[m][0] = *(const s16x8*)(sXn + base);
                A[m][1] = *(const s16x8*)(sXn + 8192 + base);
                A[m][2] = *(const s16x8*)(sXn + 16384 + base);
            }
            const int nt = half * 16 + w;
            const unsigned short* bp = wsP + W1BASE + (size_t)(kt * 32 + nt) * 1536 + l * 8;
            const s16x8 bh = *(const s16x8*)bp;
            const s16x8 bm = *(const s16x8*)(bp + 512);
            const s16x8 bl = *(const s16x8*)(bp + 1024);
            #pragma unroll
            for (int m = 0; m < 4; ++m) {
                f32x4 c = acc1[m];
                c = MFMA(A[m][1], bm, c);    // mid*mid   (~2^-18)
                c = MFMA(A[m][2], bh, c);    // lo*hi     (~2^-18)
                c = MFMA(A[m][0], bl, c);    // hi*lo     (~2^-18)
                c = MFMA(A[m][1], bh, c);    // mid*hi    (~2^-9)
                c = MFMA(A[m][0], bm, c);    // hi*mid    (~2^-9)
                c = MFMA(A[m][0], bh, c);    // hi*hi
                acc1[m] = c;
            }
        }

        // -------- bias + gelu, 3-split, write h half --------
        {
            const float b1v = b1[half * 256 + w * 16 + lr];
            #pragma unroll
            for (int m = 0; m < 4; ++m)
                #pragma unroll
                for (int r = 0; r < 4; ++r) {
                    const float h = gelu_exact(acc1[m][r] + b1v);
                    unsigned short hh, hm, hl;
                    split3(h, hh, hm, hl);
                    const int tokr = 4 * lq + r;
                    const int row  = m * 16 + tokr;
                    const int nl   = w * 16 + lr;                  // 0..255
                    const int gsw  = (nl >> 3) ^ (tokr & 7);
                    const size_t off = (size_t)row * 256 + gsw * 8 + (nl & 7);
                    sH[off]          = hh;
                    sH[16384 + off]  = hm;
                    sH[32768 + off]  = hl;
                }
        }
        __syncthreads();

        // -------- GEMM2 partial over k-half: 8 k-tiles, 2 n-tiles/wave --------
        for (int kk = 0; kk < 8; ++kk) {
            s16x8 A[4][3];
            #pragma unroll
            for (int m = 0; m < 4; ++m) {
                const int row = m * 16 + lr;
                const int gsw = (kk * 4 + lq) ^ (lr & 7);
                const size_t off = (size_t)row * 256 + (size_t)gsw * 8;
                A[m][0] = *(const s16x8*)(sH + off);
                A[m][1] = *(const s16x8*)(sH + 16384 + off);
                A[m][2] = *(const s16x8*)(sH + 32768 + off);
            }
            #pragma unroll
            for (int ntl = 0; ntl < 2; ++ntl) {
                const int fid2 = (half * 8 + kk) * 32 + (w * 2 + ntl);
                const unsigned short* bp = wsP + W2BASE + (size_t)fid2 * 1536 + l * 8;
                const s16x8 bh = *(const s16x8*)bp;
                const s16x8 bm = *(const s16x8*)(bp + 512);
                const s16x8 bl = *(const s16x8*)(bp + 1024);
                #pragma unroll
                for (int m = 0; m < 4; ++m) {
                    f32x4 c = acc2[m][ntl];
                    c = MFMA(A[m][1], bm, c);
                    c = MFMA(A[m][2], bh, c);
                    c = MFMA(A[m][0], bl, c);
                    c = MFMA(A[m][1], bh, c);
                    c = MFMA(A[m][0], bm, c);
                    c = MFMA(A[m][0], bh, c);
                    acc2[m][ntl] = c;
                }
            }
        }
        __syncthreads();
    }

    // ---------------- phase 4: bias + gumbel + quad argmax -> sC --------------
    {
        float b2v[2];
        #pragma unroll
        for (int ntl = 0; ntl < 2; ++ntl) b2v[ntl] = b2[w * 32 + ntl * 16 + lr];
        const int qq  = lr >> 2;
        const int cls = l & 3;
        #pragma unroll
        for (int m = 0; m < 4; ++m)
            #pragma unroll
            for (int ntl = 0; ntl < 2; ++ntl) {
                #pragma unroll
                for (int r = 0; r < 4; ++r) {
                    const long tg = tok0 + m * 16 + 4 * lq + r;
                    const float u = gu[tg * 512 + w * 32 + ntl * 16 + lr];
                    float v = acc2[m][ntl][r] + b2v[ntl] - logf(-logf(u));
                    int   ci = cls;
                    float v1 = __shfl_xor(v, 1); int c1 = __shfl_xor(ci, 1);
                    if (v1 > v || (v1 == v && c1 < ci)) { v = v1; ci = c1; }
                    float v2 = __shfl_xor(v, 2); int c2 = __shfl_xor(ci, 2);
                    if (v2 > v || (v2 == v && c2 < ci)) { v = v2; ci = c2; }
                    if (cls == 0) {
                        const int row = m * 16 + 4 * lq + r;
                        const int col = (w * 2 + ntl) ^ ((row & 7) << 2);
                        ((unsigned char*)(sC + row * 32 + col))[qq] = (unsigned char)ci;
                    }
                }
            }
    }
    __syncthreads();

    // ---------------- phase 5: decode (2-term MFMA, codes exact) --------------
    // wave w -> feat n-tile nt_d = w&7, token m-pair mp = w>>3
    const int nt_d = w & 7;
    const int mp   = w >> 3;
    f32x4 accd[2];
    #pragma unroll
    for (int mi = 0; mi < 2; ++mi)
        #pragma unroll
        for (int r = 0; r < 4; ++r) accd[mi][r] = 0.f;

    #pragma unroll
    for (int kt = 0; kt < 8; ++kt) {
        const unsigned short* bp = wsP + EBASE + (size_t)(kt * 8 + nt_d) * 1024 + l * 8;
        const s16x8 bh = *(const s16x8*)bp;
        const s16x8 bl = *(const s16x8*)(bp + 512);
        #pragma unroll
        for (int mi = 0; mi < 2; ++mi) {
            const int row = (mp * 2 + mi) * 16 + lr;
            const int col = (kt * 4 + lq) ^ ((row & 7) << 2);
            const unsigned cw = sC[row * 32 + col];
            s16x8 a;
            #pragma unroll
            for (int q2 = 0; q2 < 4; ++q2) {
                const unsigned c = (cw >> (8 * q2)) & 0xffu;
                a[2 * q2]     = ((c & 1u) == 0u) ? (short)0x3F80 : (short)0;
                a[2 * q2 + 1] = (((c + 1u) & 2u) != 0u) ? (short)0x3F80 : (short)0;
            }
            accd[mi] = MFMA(a, bh, accd[mi]);
            accd[mi] = MFMA(a, bl, accd[mi]);
        }
    }
    __syncthreads();

    // ---------------- phase 6: postscale norm + output ------------------------
    {
        #pragma unroll
        for (int mi = 0; mi < 2; ++mi) {
            float ps[4];
            #pragma unroll
            for (int r = 0; r < 4; ++r) {
                float s = accd[mi][r] * accd[mi][r];
                s += __shfl_xor(s, 1); s += __shfl_xor(s, 2);
                s += __shfl_xor(s, 4); s += __shfl_xor(s, 8);
                ps[r] = s;
            }
            if (lr == 0)
                *(float4*)(sPart + nt_d * 64 + (mp * 2 + mi) * 16 + 4 * lq) =
                    make_float4(ps[0], ps[1], ps[2], ps[3]);
        }
    }
    __syncthreads();
    if (tid < 64) {
        float ssum = 0.f;
        #pragma unroll
        for (int g = 0; g < 8; ++g) ssum += sPart[g * 64 + tid];
        const float post = sqrtf(ssum);
        sFac[tid] = (1.0f / (post + F_EPS)) * (sPre[tid] + F_EPS);
    }
    __syncthreads();
    {
        const float sclv = scl[nt_d * 16 + lr] + F_EPS;
        #pragma unroll
        for (int mi = 0; mi < 2; ++mi)
            #pragma unroll
            for (int r = 0; r < 4; ++r) {
                const int tokr = (mp * 2 + mi) * 16 + 4 * lq + r;
                const float o = accd[mi][r] * sFac[tokr] * sclv;
                out[(tok0 + tokr) * FEAT + nt_d * 16 + lr] = o;
            }
    }
}

extern "C" void kernel_launch(void* const* d_in, const int* in_sizes, int n_in,
                              void* d_out, int out_size, void* d_ws, size_t ws_size,
                              hipStream_t stream) {
    const float* x   = (const float*)d_in[0];
    const float* gu  = (const float*)d_in[1];
    const float* lnw = (const float*)d_in[2];
    const float* lnb = (const float*)d_in[3];
    const float* w1  = (const float*)d_in[4];
    const float* b1  = (const float*)d_in[5];
    const float* w2  = (const float*)d_in[6];
    const float* b2  = (const float*)d_in[7];
    const float* emb = (const float*)d_in[8];
    const float* scl = (const float*)d_in[9];
    float* out = (float*)d_out;

    unsigned short* wsP = (unsigned short*)d_ws;   // needs 2 MB

    hipLaunchKernelGGL(vc_pack, dim3(176), dim3(256), 0, stream, w1, w2, emb, wsP);

    const int ntok = in_sizes[0] / FEAT;           // 65536
    hipLaunchKernelGGL(vc_fused, dim3(ntok / TB), dim3(1024), 0, stream,
                       x, gu, lnw, lnb, b1, b2, scl, wsP, out);
}

// Round 5
// 336.891 us; speedup vs baseline: 2.8362x; 1.1077x over previous
//
#include <hip/hip_runtime.h>
#include <math.h>

#define FEAT  128
#define INTER 512
#define EMB   512
#define TB    32

typedef short s16x8 __attribute__((ext_vector_type(8)));
typedef float f32x4 __attribute__((ext_vector_type(4)));

static constexpr float F_EPS    = 1e-6f;
static constexpr float F_LN_EPS = 1e-5f;

#define MFMA(a,b,c) __builtin_amdgcn_mfma_f32_16x16x32_bf16(a,b,c,0,0,0)

// u16-element offsets inside wsP (total 2 MB)
#define W1BASE 0                 // 128 frags * 1536 u16 (hi|mid|lo, 512 each)
#define W2BASE 196608            // 512 frags * 1536 u16
#define EBASE  983040            // 64  frags * 1024 u16 (hi|lo)

__device__ __forceinline__ unsigned short f2bf(float f) {
    union { float f; unsigned u; } v; v.f = f;
    unsigned r = v.u + 0x7FFFu + ((v.u >> 16) & 1u);
    return (unsigned short)(r >> 16);
}
__device__ __forceinline__ float bf2f(unsigned short h) {
    union { unsigned u; float f; } v; v.u = ((unsigned)h) << 16;
    return v.f;
}
__device__ __forceinline__ void split3(float x, unsigned short& h,
                                       unsigned short& m, unsigned short& l) {
    h = f2bf(x);
    float r1 = x - bf2f(h);
    m = f2bf(r1);
    l = f2bf(r1 - bf2f(m));
}
__device__ __forceinline__ float gelu_exact(float v) {
    return 0.5f * v * (1.0f + erff(v * 0.70710678118654752440f));
}

// Pack w1/w2 into 3-split, emb into 2-split MFMA B-fragments.
// Frag lane l holds B[k = kt*32 + 8*(l>>4) + i][n = nt*16 + (l&15)], i=0..7.
__global__ __launch_bounds__(256) void vc_pack(const float* __restrict__ w1,
                                               const float* __restrict__ w2,
                                               const float* __restrict__ emb,
                                               unsigned short* __restrict__ P) {
    int id = blockIdx.x * 256 + threadIdx.x;
    int fid = id >> 6, l = id & 63;
    if (fid >= 704) return;
    int lr = l & 15, lq = l >> 4;
    float v[8];
    size_t dst;
    int three = 1;
    if (fid < 128) {
        int kt = fid >> 5, nt = fid & 31;
        const float* s = w1 + (size_t)(nt * 16 + lr) * FEAT + kt * 32 + 8 * lq;
        #pragma unroll
        for (int i = 0; i < 8; ++i) v[i] = s[i];
        dst = W1BASE + (size_t)fid * 1536;
    } else if (fid < 640) {
        int f2 = fid - 128, kt = f2 >> 5, nt = f2 & 31;
        const float* s = w2 + (size_t)(nt * 16 + lr) * INTER + kt * 32 + 8 * lq;
        #pragma unroll
        for (int i = 0; i < 8; ++i) v[i] = s[i];
        dst = W2BASE + (size_t)f2 * 1536;
    } else {
        int f3 = fid - 640, kt = f3 >> 3, nt = f3 & 7;
        #pragma unroll
        for (int i = 0; i < 8; ++i)
            v[i] = emb[(size_t)(kt * 32 + 8 * lq + i) * FEAT + nt * 16 + lr];
        dst = EBASE + (size_t)f3 * 1024;
        three = 0;
    }
    s16x8 vh, vm, vl;
    #pragma unroll
    for (int i = 0; i < 8; ++i) {
        unsigned short a, b, c;
        split3(v[i], a, b, c);
        vh[i] = (short)a; vm[i] = (short)b; vl[i] = (short)c;
    }
    *(s16x8*)(P + dst + l * 8)       = vh;
    *(s16x8*)(P + dst + 512 + l * 8) = vm;   // for emb this is the lo plane
    if (three) *(s16x8*)(P + dst + 1024 + l * 8) = vl;
}

__global__ __launch_bounds__(1024, 8) void vc_fused(
    const float* __restrict__ x,   const float* __restrict__ gu,
    const float* __restrict__ lnw, const float* __restrict__ lnb,
    const float* __restrict__ b1,  const float* __restrict__ b2,
    const float* __restrict__ scl, const unsigned short* __restrict__ wsP,
    float* __restrict__ out)
{
    // LDS map, 79104 B total -> 2 blocks/CU, 8 waves/SIMD:
    //  [0,      24576)  xn 3 planes of [2mt][4kt][64lane][8] u16 (4096 u16 each)
    //  [24576,  73728)  h  3 planes of [32][256] u16, 16B-granule XOR swizzle
    //  [73728,  77824)  sC [32][32] u32 (code bytes, col-swizzled)
    //  [77824,  79104)  sPre[32] | sPart[8][32] | sFac[32]
    __shared__ __align__(16) unsigned char smem[79104];
    unsigned short* sXn = (unsigned short*)smem;
    unsigned short* sH  = (unsigned short*)(smem + 24576);
    unsigned*       sC  = (unsigned*)(smem + 73728);
    float*          sPre  = (float*)(smem + 77824);
    float*          sPart = (float*)(smem + 77952);
    float*          sFac  = (float*)(smem + 78976);

    const int tid = threadIdx.x;
    const int w  = tid >> 6;           // wave 0..15
    const int l  = tid & 63;
    const int lr = l & 15, lq = l >> 4;
    const long tok0 = (long)blockIdx.x * TB;

    // ---------------- phase 0: scale, unit-norm, LayerNorm, 3-split frags ----
    if (tid < 512) {                   // waves 0..7; branch is wave-uniform
        const int t = tid >> 4;        // token 0..31
        const int q = tid & 15;        // feat octet 0..15
        const float* xr = x + (tok0 + t) * FEAT + q * 8;
        float v[8];
        #pragma unroll
        for (int k = 0; k < 8; ++k) v[k] = xr[k] / (scl[q * 8 + k] + F_EPS);
        float ss = 0.f;
        #pragma unroll
        for (int k = 0; k < 8; ++k) ss += v[k] * v[k];
        ss += __shfl_xor(ss, 1); ss += __shfl_xor(ss, 2);
        ss += __shfl_xor(ss, 4); ss += __shfl_xor(ss, 8);
        const float pre = sqrtf(ss);
        if (q == 0) sPre[t] = pre;
        const float ip = 1.0f / (pre + F_EPS);
        #pragma unroll
        for (int k = 0; k < 8; ++k) v[k] *= ip;
        float sm = 0.f;
        #pragma unroll
        for (int k = 0; k < 8; ++k) sm += v[k];
        sm += __shfl_xor(sm, 1); sm += __shfl_xor(sm, 2);
        sm += __shfl_xor(sm, 4); sm += __shfl_xor(sm, 8);
        const float mu = sm * (1.0f / 128.0f);
        float vv = 0.f;
        #pragma unroll
        for (int k = 0; k < 8; ++k) { float d = v[k] - mu; vv += d * d; }
        vv += __shfl_xor(vv, 1); vv += __shfl_xor(vv, 2);
        vv += __shfl_xor(vv, 4); vv += __shfl_xor(vv, 8);
        const float rst = 1.0f / sqrtf(vv * (1.0f / 128.0f) + F_LN_EPS);

        const int mt  = t >> 4;
        const int kt  = q >> 2;
        const int sub = q & 3;
        const size_t base = ((size_t)(mt * 4 + kt) * 64 + (t & 15) + 16 * sub) * 8;
        s16x8 vh, vm, vlo;
        #pragma unroll
        for (int i = 0; i < 8; ++i) {
            const float xnv = (v[i] - mu) * rst * lnw[q * 8 + i] + lnb[q * 8 + i];
            unsigned short a, b, c;
            split3(xnv, a, b, c);
            vh[i] = (short)a; vm[i] = (short)b; vlo[i] = (short)c;
        }
        *(s16x8*)(sXn + base)        = vh;
        *(s16x8*)(sXn + 4096 + base) = vm;
        *(s16x8*)(sXn + 8192 + base) = vlo;
    }
    __syncthreads();

    f32x4 acc2[2][2];
    #pragma unroll
    for (int m = 0; m < 2; ++m)
        #pragma unroll
        for (int n = 0; n < 2; ++n)
            #pragma unroll
            for (int r = 0; r < 4; ++r) acc2[m][n][r] = 0.f;

    for (int half = 0; half < 2; ++half) {
        // -------- GEMM1 over n-half: 1 n-tile/wave, 6-term split-bf16 --------
        f32x4 acc1[2];
        #pragma unroll
        for (int m = 0; m < 2; ++m)
            #pragma unroll
            for (int r = 0; r < 4; ++r) acc1[m][r] = 0.f;

        #pragma unroll
        for (int kt = 0; kt < 4; ++kt) {
            s16x8 A[2][3];
            #pragma unroll
            for (int m = 0; m < 2; ++m) {
                const size_t base = ((size_t)(m * 4 + kt) * 64 + l) * 8;
                A[m][0] = *(const s16x8*)(sXn + base);
                A[m][1] = *(const s16x8*)(sXn + 4096 + base);
                A[m][2] = *(const s16x8*)(sXn + 8192 + base);
            }
            const int nt = half * 16 + w;
            const unsigned short* bp = wsP + W1BASE + (size_t)(kt * 32 + nt) * 1536 + l * 8;
            const s16x8 bh = *(const s16x8*)bp;
            const s16x8 bm = *(const s16x8*)(bp + 512);
            const s16x8 bl = *(const s16x8*)(bp + 1024);
            #pragma unroll
            for (int m = 0; m < 2; ++m) {
                f32x4 c = acc1[m];
                c = MFMA(A[m][1], bm, c);    // mid*mid   (~2^-18)
                c = MFMA(A[m][2], bh, c);    // lo*hi     (~2^-18)
                c = MFMA(A[m][0], bl, c);    // hi*lo     (~2^-18)
                c = MFMA(A[m][1], bh, c);    // mid*hi    (~2^-9)
                c = MFMA(A[m][0], bm, c);    // hi*mid    (~2^-9)
                c = MFMA(A[m][0], bh, c);    // hi*hi
                acc1[m] = c;
            }
        }

        // -------- bias + gelu, 3-split, write h half --------
        {
            const float b1v = b1[half * 256 + w * 16 + lr];
            #pragma unroll
            for (int m = 0; m < 2; ++m)
                #pragma unroll
                for (int r = 0; r < 4; ++r) {
                    const float h = gelu_exact(acc1[m][r] + b1v);
                    unsigned short hh, hm, hl;
                    split3(h, hh, hm, hl);
                    const int tokr = 4 * lq + r;
                    const int row  = m * 16 + tokr;
                    const int nl   = w * 16 + lr;                  // 0..255
                    const int gsw  = (nl >> 3) ^ (tokr & 7);
                    const size_t off = (size_t)row * 256 + gsw * 8 + (nl & 7);
                    sH[off]          = hh;
                    sH[8192 + off]   = hm;
                    sH[16384 + off]  = hl;
                }
        }
        __syncthreads();

        // -------- GEMM2 partial over k-half: 8 k-tiles, 2 n-tiles/wave --------
        for (int kk = 0; kk < 8; ++kk) {
            s16x8 A[2][3];
            #pragma unroll
            for (int m = 0; m < 2; ++m) {
                const int row = m * 16 + lr;
                const int gsw = (kk * 4 + lq) ^ (lr & 7);
                const size_t off = (size_t)row * 256 + (size_t)gsw * 8;
                A[m][0] = *(const s16x8*)(sH + off);
                A[m][1] = *(const s16x8*)(sH + 8192 + off);
                A[m][2] = *(const s16x8*)(sH + 16384 + off);
            }
            #pragma unroll
            for (int ntl = 0; ntl < 2; ++ntl) {
                const int fid2 = (half * 8 + kk) * 32 + (w * 2 + ntl);
                const unsigned short* bp = wsP + W2BASE + (size_t)fid2 * 1536 + l * 8;
                const s16x8 bh = *(const s16x8*)bp;
                const s16x8 bm = *(const s16x8*)(bp + 512);
                const s16x8 bl = *(const s16x8*)(bp + 1024);
                #pragma unroll
                for (int m = 0; m < 2; ++m) {
                    f32x4 c = acc2[m][ntl];
                    c = MFMA(A[m][1], bm, c);
                    c = MFMA(A[m][2], bh, c);
                    c = MFMA(A[m][0], bl, c);
                    c = MFMA(A[m][1], bh, c);
                    c = MFMA(A[m][0], bm, c);
                    c = MFMA(A[m][0], bh, c);
                    acc2[m][ntl] = c;
                }
            }
        }
        __syncthreads();
    }

    // ---------------- phase 4: bias + gumbel + quad argmax -> sC --------------
    {
        float b2v[2];
        #pragma unroll
        for (int ntl = 0; ntl < 2; ++ntl) b2v[ntl] = b2[w * 32 + ntl * 16 + lr];
        const int qq  = lr >> 2;
        const int cls = l & 3;
        #pragma unroll
        for (int m = 0; m < 2; ++m)
            #pragma unroll
            for (int ntl = 0; ntl < 2; ++ntl) {
                #pragma unroll
                for (int r = 0; r < 4; ++r) {
                    const long tg = tok0 + m * 16 + 4 * lq + r;
                    const float u = gu[tg * 512 + w * 32 + ntl * 16 + lr];
                    float v = acc2[m][ntl][r] + b2v[ntl] - logf(-logf(u));
                    int   ci = cls;
                    float v1 = __shfl_xor(v, 1); int c1 = __shfl_xor(ci, 1);
                    if (v1 > v || (v1 == v && c1 < ci)) { v = v1; ci = c1; }
                    float v2 = __shfl_xor(v, 2); int c2 = __shfl_xor(ci, 2);
                    if (v2 > v || (v2 == v && c2 < ci)) { v = v2; ci = c2; }
                    if (cls == 0) {
                        const int row = m * 16 + 4 * lq + r;
                        const int col = (w * 2 + ntl) ^ ((row & 7) << 2);
                        ((unsigned char*)(sC + row * 32 + col))[qq] = (unsigned char)ci;
                    }
                }
            }
    }
    __syncthreads();

    // ---------------- phase 5: decode (2-term MFMA, codes exact) --------------
    // wave w -> feat n-tile nt_d = w&7, token m-tile mp = w>>3
    const int nt_d = w & 7;
    const int mp   = w >> 3;
    f32x4 accd;
    #pragma unroll
    for (int r = 0; r < 4; ++r) accd[r] = 0.f;

    #pragma unroll
    for (int kt = 0; kt < 8; ++kt) {
        const unsigned short* bp = wsP + EBASE + (size_t)(kt * 8 + nt_d) * 1024 + l * 8;
        const s16x8 bh = *(const s16x8*)bp;
        const s16x8 bl = *(const s16x8*)(bp + 512);
        const int row = mp * 16 + lr;
        const int col = (kt * 4 + lq) ^ ((row & 7) << 2);
        const unsigned cw = sC[row * 32 + col];
        s16x8 a;
        #pragma unroll
        for (int q2 = 0; q2 < 4; ++q2) {
            const unsigned c = (cw >> (8 * q2)) & 0xffu;
            a[2 * q2]     = ((c & 1u) == 0u) ? (short)0x3F80 : (short)0;
            a[2 * q2 + 1] = (((c + 1u) & 2u) != 0u) ? (short)0x3F80 : (short)0;
        }
        accd = MFMA(a, bh, accd);
        accd = MFMA(a, bl, accd);
    }
    __syncthreads();

    // ---------------- phase 6: postscale norm + output ------------------------
    {
        float ps[4];
        #pragma unroll
        for (int r = 0; r < 4; ++r) {
            float s = accd[r] * accd[r];
            s += __shfl_xor(s, 1); s += __shfl_xor(s, 2);
            s += __shfl_xor(s, 4); s += __shfl_xor(s, 8);
            ps[r] = s;
        }
        if (lr == 0)
            *(float4*)(sPart + nt_d * 32 + mp * 16 + 4 * lq) =
                make_float4(ps[0], ps[1], ps[2], ps[3]);
    }
    __syncthreads();
    if (tid < 32) {
        float ssum = 0.f;
        #pragma unroll
        for (int g = 0; g < 8; ++g) ssum += sPart[g * 32 + tid];
        const float post = sqrtf(ssum);
        sFac[tid] = (1.0f / (post + F_EPS)) * (sPre[tid] + F_EPS);
    }
    __syncthreads();
    {
        const float sclv = scl[nt_d * 16 + lr] + F_EPS;
        #pragma unroll
        for (int r = 0; r < 4; ++r) {
            const int tokr = mp * 16 + 4 * lq + r;
            const float o = accd[r] * sFac[tokr] * sclv;
            out[(tok0 + tokr) * FEAT + nt_d * 16 + lr] = o;
        }
    }
}

extern "C" void kernel_launch(void* const* d_in, const int* in_sizes, int n_in,
                              void* d_out, int out_size, void* d_ws, size_t ws_size,
                              hipStream_t stream) {
    const float* x   = (const float*)d_in[0];
    const float* gu  = (const float*)d_in[1];
    const float* lnw = (const float*)d_in[2];
    const float* lnb = (const float*)d_in[3];
    const float* w1  = (const float*)d_in[4];
    const float* b1  = (const float*)d_in[5];
    const float* w2  = (const float*)d_in[6];
    const float* b2  = (const float*)d_in[7];
    const float* emb = (const float*)d_in[8];
    const float* scl = (const float*)d_in[9];
    float* out = (float*)d_out;

    unsigned short* wsP = (unsigned short*)d_ws;   // needs 2 MB

    hipLaunchKernelGGL(vc_pack, dim3(176), dim3(256), 0, stream, w1, w2, emb, wsP);

    const int ntok = in_sizes[0] / FEAT;           // 65536
    hipLaunchKernelGGL(vc_fused, dim3(ntok / TB), dim3(1024), 0, stream,
                       x, gu, lnw, lnb, b1, b2, scl, wsP, out);
}